// Round 4
// baseline (1774.339 us; speedup 1.0000x reference)
//
#include <hip/hip_runtime.h>
#include <hip/hip_bf16.h>

using bf16 = __hip_bfloat16;

// Problem constants: B=32, N=8, Q=D*H*W=1536, K=H*W=256, CELL=128, EMB=32
// All inputs float32, all outputs float32 (established round 3).
#define QT_ 16        // q-tile per block
#define KCH 16        // k rows of v staged in LDS per chunk
#define VROW 20       // v-chunk row stride in floats (80 B, 16B multiple)
#define W2R 264       // Wq2^T LDS row stride in bf16 (528 B, 16B multiple)

#define WS_EMBO 0     // workspace: emb_o 256*32 f32 (32 KB)

__device__ __forceinline__ float bflo(unsigned u){ union{unsigned i; float f;} c; c.i = u<<16; return c.f; }
__device__ __forceinline__ float bfhi(unsigned u){ union{unsigned i; float f;} c; c.i = u & 0xffff0000u; return c.f; }
__device__ __forceinline__ float sigmoidf_(float x){ return 1.f/(1.f+__expf(-x)); }

// unpack 8 bf16 (uint4) -> 8 f32
__device__ __forceinline__ void unp8(uint4 u, float* o){
  o[0]=bflo(u.x); o[1]=bfhi(u.x); o[2]=bflo(u.y); o[3]=bfhi(u.y);
  o[4]=bflo(u.z); o[5]=bfhi(u.z); o[6]=bflo(u.w); o[7]=bfhi(u.w);
}

// ---------------- helpers ----------------
__device__ __forceinline__ void relpose(const float* mo, const float* mq, float* o) {
  float a=mo[0],bb=mo[1],c=mo[2], d=mo[4],e=mo[5],f=mo[6], g=mo[8],h=mo[9],i9=mo[10];
  float A = e*i9-f*h, Bc = f*g-d*i9, C = d*h-e*g;
  float inv = 1.f/(a*A + bb*Bc + c*C);
  float r00=A*inv,  r01=(c*h-bb*i9)*inv, r02=(bb*f-c*e)*inv;
  float r10=Bc*inv, r11=(a*i9-c*g)*inv,  r12=(c*d-a*f)*inv;
  float r20=C*inv,  r21=(bb*g-a*h)*inv,  r22=(a*e-bb*d)*inv;
  float tx = mq[3]-mo[3], ty = mq[7]-mo[7], tz = mq[11]-mo[11];
  o[0]=r00*mq[0]+r01*mq[4]+r02*mq[8];  o[1]=r00*mq[1]+r01*mq[5]+r02*mq[9];
  o[2]=r00*mq[2]+r01*mq[6]+r02*mq[10]; o[3]=r00*tx+r01*ty+r02*tz;
  o[4]=r10*mq[0]+r11*mq[4]+r12*mq[8];  o[5]=r10*mq[1]+r11*mq[5]+r12*mq[9];
  o[6]=r10*mq[2]+r11*mq[6]+r12*mq[10]; o[7]=r10*tx+r11*ty+r12*tz;
  o[8]=r20*mq[0]+r21*mq[4]+r22*mq[8];  o[9]=r20*mq[1]+r21*mq[5]+r22*mq[9];
  o[10]=r20*mq[2]+r21*mq[6]+r22*mq[10]; o[11]=r20*tx+r21*ty+r22*tz;
}

__device__ __forceinline__ void quat7(const float* m, float* o) {
  float m00=m[0], m01=m[1], m02=m[2];
  float m10=m[4], m11=m[5], m12=m[6];
  float m20=m[8], m21=m[9], m22=m[10];
  float t,q0,q1,q2,q3;
  if (m22 < 0.f) {
    if (m00 > m11) { t=1.f+m00-m11-m22; q0=t;        q1=m01+m10; q2=m20+m02; q3=m12-m21; }
    else           { t=1.f-m00+m11-m22; q0=m01+m10; q1=t;        q2=m12+m21; q3=m20-m02; }
  } else {
    if (m00 < -m11){ t=1.f-m00-m11+m22; q0=m20+m02; q1=m12+m21; q2=t;        q3=m01-m10; }
    else           { t=1.f+m00+m11+m22; q0=m12-m21; q1=m20-m02; q2=m01-m10; q3=t;        }
  }
  float s = 0.5f / sqrtf(t);
  o[0]=m[3]; o[1]=m[7]; o[2]=m[11];
  o[3]=q0*s; o[4]=q1*s; o[5]=q2*s; o[6]=q3*s;
}

// ---------------- kernel 1: quaternion outputs ----------------
__global__ void k_pose(const float* __restrict__ pose_o, const float* __restrict__ pose_q,
                       float* __restrict__ out_qo, float* __restrict__ out_qq) {
  int t = threadIdx.x;              // 0..255 = bn
  float mo[12];
  #pragma unroll
  for (int i=0;i<12;i++) mo[i] = pose_o[t*12+i];
  float q7[7]; quat7(mo, q7);
  #pragma unroll
  for (int i=0;i<7;i++) out_qo[t*7+i] = q7[i];

  if (t < 32) {
    float mqq[12];
    #pragma unroll
    for (int i=0;i<12;i++) mqq[i] = pose_q[t*12+i];
    float q7b[7]; quat7(mqq, q7b);
    #pragma unroll
    for (int i=0;i<7;i++) out_qq[t*7+i] = q7b[i];
  }
}

// ---------------- kernel 2: shared key embeddings ----------------
__global__ void k_embo(const float* __restrict__ Wk1, const float* __restrict__ bk1,
                       const float* __restrict__ Wk2, const float* __restrict__ bk2,
                       float* __restrict__ ws_embo) {
  int k = threadIdx.x;  // 0..255
  float x0 = -1.f + (float)(k>>4)*(2.f/15.f);
  float x1 = -1.f + (float)(k&15)*(2.f/15.f);
  float acc[32];
  #pragma unroll
  for (int e=0;e<32;e++) acc[e] = bk2[e];
  for (int j=0;j<128;j++) {
    float hj = fmaxf(fmaf(x0, Wk1[j], fmaf(x1, Wk1[128+j], bk1[j])), 0.f);
    #pragma unroll
    for (int u=0;u<8;u++) {
      float4 w = *(const float4*)&Wk2[j*32+u*4];
      acc[u*4+0] = fmaf(hj, w.x, acc[u*4+0]);
      acc[u*4+1] = fmaf(hj, w.y, acc[u*4+1]);
      acc[u*4+2] = fmaf(hj, w.z, acc[u*4+2]);
      acc[u*4+3] = fmaf(hj, w.w, acc[u*4+3]);
    }
  }
  #pragma unroll
  for (int e=0;e<32;e++) ws_embo[k*32+e] = acc[e];
}

// ---------------- kernel 3: fused emb_q / mask / attention / fusion ----------------
__global__ void __launch_bounds__(256, 3)
k_main(const float* __restrict__ vc,
       const float* __restrict__ pose_o, const float* __restrict__ pose_q,
       const float* __restrict__ ws_embo,
       const float* __restrict__ Wq1, const float* __restrict__ bq1,
       const float* __restrict__ Wq2, const float* __restrict__ bq2,
       const float* __restrict__ Wa1, const float* __restrict__ ba1,
       const float* __restrict__ Wa2, const float* __restrict__ ba2,
       float* __restrict__ out) {
  __shared__ __align__(16) float s_buf[16][260];   // hidden[q][h] then logits/probs[q][k]
  __shared__ __align__(16) bf16  s_w2t[32*W2R];    // Wq2^T [e][h], bf16-compressed
  __shared__ __align__(16) float s_vk[128*VROW];   // v chunk [c][k-chunk]
  __shared__ __align__(16) bf16  s_wa1[32*64];     // Wa1 [e][u], bf16-compressed
  __shared__ __align__(16) float s_embq[16][32];
  __shared__ float s_pt[8][12];
  __shared__ float s_redA[16][16];   // mask partials
  __shared__ float s_redB[16][16];   // max, then exp-sums
  // LDS total: 16640+16896+10240+4096+2048+384+1024+1024 = 52352 B -> 3 blocks/CU

  const int tid = threadIdx.x;
  const int b = blockIdx.y;
  const int qt0 = blockIdx.x * QT_;
  const int q_l = tid >> 4, l16 = tid & 15;

  // ---- one-time staging ----
  float wcol[15];
  #pragma unroll
  for (int i=0;i<15;i++) wcol[i] = Wq1[i*256+tid];
  const float b1 = bq1[tid];
  for (int e=0;e<32;e++) s_w2t[e*W2R + tid] = __float2bfloat16(Wq2[tid*32+e]);
  #pragma unroll
  for (int i=0;i<8;i++) s_wa1[tid*8+i] = __float2bfloat16(Wa1[tid*8+i]);
  if (tid < 8) {   // per-block relative poses (redundant across blocks, trivial)
    float mo[12], mq[12], pt[12];
    #pragma unroll
    for (int i=0;i<12;i++) mo[i] = pose_o[(b*8+tid)*12+i];
    #pragma unroll
    for (int i=0;i<12;i++) mq[i] = pose_q[b*12+i];
    relpose(mo, mq, pt);
    #pragma unroll
    for (int i=0;i<12;i++) s_pt[tid][i] = pt[i];
  }
  float ek[32];
  {
    const float4* p = (const float4*)&ws_embo[tid*32];
    #pragma unroll
    for (int u=0;u<8;u++) { float4 v = p[u]; ek[u*4]=v.x; ek[u*4+1]=v.y; ek[u*4+2]=v.z; ek[u*4+3]=v.w; }
  }
  const float bq2a = bq2[l16], bq2b = bq2[l16+16];
  float ba1v[4], wa2v[4];
  { float4 t4 = *(const float4*)&ba1[l16*4]; ba1v[0]=t4.x; ba1v[1]=t4.y; ba1v[2]=t4.z; ba1v[3]=t4.w; }
  { float4 t4 = *(const float4*)&Wa2[l16*4]; wa2v[0]=t4.x; wa2v[1]=t4.y; wa2v[2]=t4.z; wa2v[3]=t4.w; }
  const float ba2v = ba2[0];

  float acc[8];
  #pragma unroll
  for (int j=0;j<8;j++) acc[j]=0.f;

  __syncthreads();

  for (int n=0;n<8;n++) {
    const int bn = b*8+n;
    // ---- layer-1 hidden: thread owns hidden unit h=tid for all 16 q ----
    float base = b1;
    #pragma unroll
    for (int i=0;i<12;i++) base = fmaf(s_pt[n][i], wcol[i], base);
    #pragma unroll
    for (int q=0;q<16;q++) {
      int qg = qt0+q;
      float c0 = (float)(qg>>8) * 0.2f;
      float c1 = -1.f + (float)((qg>>4)&15)*(2.f/15.f);
      float c2 = -1.f + (float)(qg&15)*(2.f/15.f);
      float hv = fmaf(c2, wcol[14], fmaf(c1, wcol[13], fmaf(c0, wcol[12], base)));
      s_buf[q][tid] = fmaxf(hv, 0.f);
    }
    __syncthreads();                               // A
    // ---- layer-2: emb_q, thread owns (q_l, e=l16) and (q_l, e=l16+16) ----
    {
      float ea = bq2a, eb = bq2b;
      const bf16* w2a = &s_w2t[l16*W2R];
      const bf16* w2b = &s_w2t[(l16+16)*W2R];
      #pragma unroll 4
      for (int h=0; h<256; h+=8) {
        float4 h0 = *(const float4*)&s_buf[q_l][h];
        float4 h1 = *(const float4*)&s_buf[q_l][h+4];
        float wa[8], wb[8];
        unp8(*(const uint4*)&w2a[h], wa);
        unp8(*(const uint4*)&w2b[h], wb);
        ea = fmaf(h0.x, wa[0], ea); ea = fmaf(h0.y, wa[1], ea);
        ea = fmaf(h0.z, wa[2], ea); ea = fmaf(h0.w, wa[3], ea);
        ea = fmaf(h1.x, wa[4], ea); ea = fmaf(h1.y, wa[5], ea);
        ea = fmaf(h1.z, wa[6], ea); ea = fmaf(h1.w, wa[7], ea);
        eb = fmaf(h0.x, wb[0], eb); eb = fmaf(h0.y, wb[1], eb);
        eb = fmaf(h0.z, wb[2], eb); eb = fmaf(h0.w, wb[3], eb);
        eb = fmaf(h1.x, wb[4], eb); eb = fmaf(h1.y, wb[5], eb);
        eb = fmaf(h1.z, wb[6], eb); eb = fmaf(h1.w, wb[7], eb);
      }
      s_embq[q_l][l16] = ea; s_embq[q_l][l16+16] = eb;
    }
    __syncthreads();                               // B
    // ---- mask partials (u = l16*4..+4) ----
    {
      float h2[4] = {ba1v[0],ba1v[1],ba1v[2],ba1v[3]};
      #pragma unroll 4
      for (int e=0;e<32;e++) {
        float ev = s_embq[q_l][e];
        uint2 w = *(const uint2*)&s_wa1[e*64 + l16*4];
        h2[0] = fmaf(ev, bflo(w.x), h2[0]);
        h2[1] = fmaf(ev, bfhi(w.x), h2[1]);
        h2[2] = fmaf(ev, bflo(w.y), h2[2]);
        h2[3] = fmaf(ev, bfhi(w.y), h2[3]);
      }
      float mp = 0.f;
      #pragma unroll
      for (int j=0;j<4;j++) mp += fmaxf(h2[j],0.f)*wa2v[j];
      s_redA[q_l][l16] = mp;
    }
    // ---- logits: thread owns k=tid, emb_o row in registers ----
    #pragma unroll 1
    for (int q=0;q<16;q++) {
      float lg = 0.f;
      const float4* eq = (const float4*)&s_embq[q][0];
      #pragma unroll
      for (int u=0;u<8;u++) {
        float4 v = eq[u];
        lg = fmaf(v.x, ek[u*4+0], lg); lg = fmaf(v.y, ek[u*4+1], lg);
        lg = fmaf(v.z, ek[u*4+2], lg); lg = fmaf(v.w, ek[u*4+3], lg);
      }
      s_buf[q][tid] = lg;
    }
    __syncthreads();                               // C
    // ---- softmax over k=256 (thread owns k = l16*16..+16 of row q_l) ----
    float vloc[16];
    {
      const float4* row = (const float4*)&s_buf[q_l][l16*16];
      float lmax = -1e30f;
      #pragma unroll
      for (int u=0;u<4;u++) {
        float4 v = row[u];
        vloc[u*4]=v.x; vloc[u*4+1]=v.y; vloc[u*4+2]=v.z; vloc[u*4+3]=v.w;
        lmax = fmaxf(lmax, fmaxf(fmaxf(v.x,v.y),fmaxf(v.z,v.w)));
      }
      s_redB[q_l][l16] = lmax;
    }
    __syncthreads();                               // D
    float rmax = s_redB[q_l][0];
    #pragma unroll
    for (int j=1;j<16;j++) rmax = fmaxf(rmax, s_redB[q_l][j]);
    __syncthreads();                               // D2 (redB reused for sums)
    {
      float psum = 0.f;
      #pragma unroll
      for (int u=0;u<16;u++) { float e = __expf(vloc[u]-rmax); vloc[u]=e; psum += e; }
      float4* row = (float4*)&s_buf[q_l][l16*16];
      #pragma unroll
      for (int u=0;u<4;u++) row[u] = make_float4(vloc[u*4],vloc[u*4+1],vloc[u*4+2],vloc[u*4+3]);
      s_redB[q_l][l16] = psum;
    }
    __syncthreads();                               // E
    float ssum = 0.f, msum = ba2v;
    #pragma unroll
    for (int j=0;j<16;j++) { ssum += s_redB[q_l][j]; msum += s_redA[q_l][j]; }
    const float rs = sigmoidf_(msum) / ssum;       // mask * softmax-normalizer
    // ---- vatt: pacc[j] for c = l16+16j; k in chunks of KCH ----
    float pacc[8];
    #pragma unroll
    for (int j=0;j<8;j++) pacc[j]=0.f;
    const float* vbase = vc + (size_t)bn*32768;
    for (int ch=0; ch<256/KCH; ch++) {
      __syncthreads();                             // guard s_vk overwrite
      #pragma unroll
      for (int i=0;i<2;i++) {
        int idx = tid + i*256;                     // 0..511
        int c = idx >> 2, kp = idx & 3;
        *(float4*)&s_vk[c*VROW + kp*4] = *(const float4*)&vbase[c*256 + ch*KCH + kp*4];
      }
      __syncthreads();
      const float* prow = &s_buf[q_l][ch*KCH];
      #pragma unroll
      for (int kg=0; kg<KCH/8; kg++) {
        float4 p0 = *(const float4*)&prow[kg*8];
        float4 p1 = *(const float4*)&prow[kg*8+4];
        #pragma unroll
        for (int j=0;j<8;j++) {
          const float* vr = &s_vk[(l16 + 16*j)*VROW + kg*8];
          float4 v0 = *(const float4*)vr;
          float4 v1 = *(const float4*)(vr+4);
          pacc[j] = fmaf(p0.x, v0.x, pacc[j]);
          pacc[j] = fmaf(p0.y, v0.y, pacc[j]);
          pacc[j] = fmaf(p0.z, v0.z, pacc[j]);
          pacc[j] = fmaf(p0.w, v0.w, pacc[j]);
          pacc[j] = fmaf(p1.x, v1.x, pacc[j]);
          pacc[j] = fmaf(p1.y, v1.y, pacc[j]);
          pacc[j] = fmaf(p1.z, v1.z, pacc[j]);
          pacc[j] = fmaf(p1.w, v1.w, pacc[j]);
        }
      }
    }
    #pragma unroll
    for (int j=0;j<8;j++) acc[j] = fmaf(rs, pacc[j], acc[j]);
    __syncthreads();                               // F: before next n's writes
  }
  // ---- epilogue: out[b][c][qg] = sigmoid(acc), c = l16+16j ----
  const int qg = qt0 + q_l;
  const size_t obase = (size_t)b*(128*1536) + qg;
  #pragma unroll
  for (int j=0;j<8;j++)
    out[obase + (size_t)(l16 + 16*j)*1536] = sigmoidf_(acc[j]);
}

extern "C" void kernel_launch(void* const* d_in, const int* in_sizes, int n_in,
                              void* d_out, int out_size, void* d_ws, size_t ws_size,
                              hipStream_t stream) {
  const float* view_cell = (const float*)d_in[0];
  const float* pose_o = (const float*)d_in[1];
  const float* pose_q = (const float*)d_in[2];
  const float* Wk1 = (const float*)d_in[3];
  const float* bk1 = (const float*)d_in[4];
  const float* Wk2 = (const float*)d_in[5];
  const float* bk2 = (const float*)d_in[6];
  const float* Wq1 = (const float*)d_in[7];
  const float* bq1 = (const float*)d_in[8];
  const float* Wq2 = (const float*)d_in[9];
  const float* bq2 = (const float*)d_in[10];
  const float* Wa1 = (const float*)d_in[11];
  const float* ba1 = (const float*)d_in[12];
  const float* Wa2 = (const float*)d_in[13];
  const float* ba2 = (const float*)d_in[14];

  float* out = (float*)d_out;
  float* out_qo = out + 6291456;          // 32*128*1536
  float* out_qq = out + 6291456 + 1792;   // + 32*8*7

  float* ws_embo = (float*)((char*)d_ws + WS_EMBO);

  hipLaunchKernelGGL(k_pose, dim3(1), dim3(256), 0, stream,
                     pose_o, pose_q, out_qo, out_qq);
  hipLaunchKernelGGL(k_embo, dim3(1), dim3(256), 0, stream,
                     Wk1, bk1, Wk2, bk2, ws_embo);
  hipLaunchKernelGGL(k_main, dim3(96, 32), dim3(256), 0, stream,
                     view_cell, pose_o, pose_q, ws_embo, Wq1, bq1, Wq2, bq2,
                     Wa1, ba1, Wa2, ba2, out);
}

// Round 5
// 360.243 us; speedup vs baseline: 4.9254x; 4.9254x over previous
//
#include <hip/hip_runtime.h>
#include <hip/hip_bf16.h>

using bf16 = __hip_bfloat16;
typedef __bf16 bfrag __attribute__((ext_vector_type(8)));
typedef float  ffrag __attribute__((ext_vector_type(4)));

// Problem: B=32, N=8, Q=1536, K=256, CELL=128, EMB=32. Inputs f32, outputs f32.
#define QT_ 16

// workspace layout (bytes)
#define WS_EO   0         // emb_o bf16 [256 key][32 e]              16 KB
#define WS_W2T  16384     // Wq2^T bf16 [32 e][256 k]                16 KB
#define WS_VBF  65536     // view_cell bf16 [256 bn][128 c][256 k]   16 MB (optional)

__device__ __forceinline__ float sigmoidf_(float x){ return 1.f/(1.f+__expf(-x)); }

// ---------------- helpers ----------------
__device__ __forceinline__ void relpose(const float* mo, const float* mq, float* o) {
  float a=mo[0],bb=mo[1],c=mo[2], d=mo[4],e=mo[5],f=mo[6], g=mo[8],h=mo[9],i9=mo[10];
  float A = e*i9-f*h, Bc = f*g-d*i9, C = d*h-e*g;
  float inv = 1.f/(a*A + bb*Bc + c*C);
  float r00=A*inv,  r01=(c*h-bb*i9)*inv, r02=(bb*f-c*e)*inv;
  float r10=Bc*inv, r11=(a*i9-c*g)*inv,  r12=(c*d-a*f)*inv;
  float r20=C*inv,  r21=(bb*g-a*h)*inv,  r22=(a*e-bb*d)*inv;
  float tx = mq[3]-mo[3], ty = mq[7]-mo[7], tz = mq[11]-mo[11];
  o[0]=r00*mq[0]+r01*mq[4]+r02*mq[8];  o[1]=r00*mq[1]+r01*mq[5]+r02*mq[9];
  o[2]=r00*mq[2]+r01*mq[6]+r02*mq[10]; o[3]=r00*tx+r01*ty+r02*tz;
  o[4]=r10*mq[0]+r11*mq[4]+r12*mq[8];  o[5]=r10*mq[1]+r11*mq[5]+r12*mq[9];
  o[6]=r10*mq[2]+r11*mq[6]+r12*mq[10]; o[7]=r10*tx+r11*ty+r12*tz;
  o[8]=r20*mq[0]+r21*mq[4]+r22*mq[8];  o[9]=r20*mq[1]+r21*mq[5]+r22*mq[9];
  o[10]=r20*mq[2]+r21*mq[6]+r22*mq[10]; o[11]=r20*tx+r21*ty+r22*tz;
}

__device__ __forceinline__ void quat7(const float* m, float* o) {
  float m00=m[0], m01=m[1], m02=m[2];
  float m10=m[4], m11=m[5], m12=m[6];
  float m20=m[8], m21=m[9], m22=m[10];
  float t,q0,q1,q2,q3;
  if (m22 < 0.f) {
    if (m00 > m11) { t=1.f+m00-m11-m22; q0=t;        q1=m01+m10; q2=m20+m02; q3=m12-m21; }
    else           { t=1.f-m00+m11-m22; q0=m01+m10; q1=t;        q2=m12+m21; q3=m20-m02; }
  } else {
    if (m00 < -m11){ t=1.f-m00-m11+m22; q0=m20+m02; q1=m12+m21; q2=t;        q3=m01-m10; }
    else           { t=1.f+m00+m11+m22; q0=m12-m21; q1=m20-m02; q2=m01-m10; q3=t;        }
  }
  float s = 0.5f / sqrtf(t);
  o[0]=m[3]; o[1]=m[7]; o[2]=m[11];
  o[3]=q0*s; o[4]=q1*s; o[5]=q2*s; o[6]=q3*s;
}

// ---------------- kernel 1: quaternion outputs (f32) ----------------
__global__ void k_pose(const float* __restrict__ pose_o, const float* __restrict__ pose_q,
                       float* __restrict__ out_qo, float* __restrict__ out_qq) {
  int t = threadIdx.x;
  float mo[12];
  #pragma unroll
  for (int i=0;i<12;i++) mo[i] = pose_o[t*12+i];
  float q7[7]; quat7(mo, q7);
  #pragma unroll
  for (int i=0;i<7;i++) out_qo[t*7+i] = q7[i];
  if (t < 32) {
    float mqq[12];
    #pragma unroll
    for (int i=0;i<12;i++) mqq[i] = pose_q[t*12+i];
    float q7b[7]; quat7(mqq, q7b);
    #pragma unroll
    for (int i=0;i<7;i++) out_qq[t*7+i] = q7b[i];
  }
}

// ---------------- kernel 2: key embeddings -> ws_eo bf16 [key][32] ----------------
__global__ void k_embo(const float* __restrict__ Wk1, const float* __restrict__ bk1,
                       const float* __restrict__ Wk2, const float* __restrict__ bk2,
                       bf16* __restrict__ ws_eo) {
  int k = threadIdx.x;
  float x0 = -1.f + (float)(k>>4)*(2.f/15.f);
  float x1 = -1.f + (float)(k&15)*(2.f/15.f);
  float acc[32];
  #pragma unroll
  for (int e=0;e<32;e++) acc[e] = bk2[e];
  for (int j=0;j<128;j++) {
    float hj = fmaxf(fmaf(x0, Wk1[j], fmaf(x1, Wk1[128+j], bk1[j])), 0.f);
    #pragma unroll
    for (int u=0;u<8;u++) {
      float4 w = *(const float4*)&Wk2[j*32+u*4];
      acc[u*4+0] = fmaf(hj, w.x, acc[u*4+0]);
      acc[u*4+1] = fmaf(hj, w.y, acc[u*4+1]);
      acc[u*4+2] = fmaf(hj, w.z, acc[u*4+2]);
      acc[u*4+3] = fmaf(hj, w.w, acc[u*4+3]);
    }
  }
  #pragma unroll
  for (int e=0;e<32;e++) ws_eo[k*32+e] = __float2bfloat16(acc[e]);
}

// ---------------- kernel 2b: Wq2 [256k][32e] f32 -> ws_w2t bf16 [e][k] ----------------
__global__ void k_w2t(const float* __restrict__ Wq2, bf16* __restrict__ ws_w2t) {
  int k = threadIdx.x;  // 0..255
  #pragma unroll
  for (int u=0;u<8;u++) {
    float4 w = *(const float4*)&Wq2[k*32+u*4];
    ws_w2t[(u*4+0)*256+k] = __float2bfloat16(w.x);
    ws_w2t[(u*4+1)*256+k] = __float2bfloat16(w.y);
    ws_w2t[(u*4+2)*256+k] = __float2bfloat16(w.z);
    ws_w2t[(u*4+3)*256+k] = __float2bfloat16(w.w);
  }
}

// ---------------- kernel 2c: view_cell f32 -> bf16 (optional, ws permitting) ----------
__global__ void k_vconv(const float* __restrict__ vc, bf16* __restrict__ vbf) {
  int idx = (blockIdx.x*256 + threadIdx.x)*8;
  float4 a = *(const float4*)&vc[idx];
  float4 b = *(const float4*)&vc[idx+4];
  bf16 o[8] __attribute__((aligned(16)));
  o[0]=__float2bfloat16(a.x); o[1]=__float2bfloat16(a.y);
  o[2]=__float2bfloat16(a.z); o[3]=__float2bfloat16(a.w);
  o[4]=__float2bfloat16(b.x); o[5]=__float2bfloat16(b.y);
  o[6]=__float2bfloat16(b.z); o[7]=__float2bfloat16(b.w);
  *(uint4*)&vbf[idx] = *(const uint4*)o;
}

// ---------------- kernel 3: fused MFMA pipeline ----------------
// grid (96 q-tiles, 32 b), 256 threads = 4 waves.
// Fragment layouts (gfx950 16x16x32_bf16, HW-verified in guide):
//   A[m=lane&15][k=quad*8+j]   B[k=quad*8+j][n=lane&15]   D[row=quad*4+r][col=lane&15]
template<bool PRE>
__global__ void __launch_bounds__(256, 4)
k_main(const float* __restrict__ vc, const bf16* __restrict__ vbf,
       const float* __restrict__ pose_o, const float* __restrict__ pose_q,
       const bf16* __restrict__ ws_eo, const bf16* __restrict__ ws_w2t,
       const float* __restrict__ Wq1, const float* __restrict__ bq1,
       const float* __restrict__ bq2,
       const float* __restrict__ Wa1, const float* __restrict__ ba1,
       const float* __restrict__ Wa2, const float* __restrict__ ba2,
       float* __restrict__ out) {
  __shared__ __align__(16) bf16  s_h[16*264];    // hidden[q][h], A-frag layout, pad 264
  __shared__ __align__(16) bf16  s_p[16*264];    // P exp[q][key], A-frag layout
  __shared__ __align__(16) bf16  s_eqA[16*40];   // emb_q[q][e], A-frag layout
  __shared__ __align__(16) bf16  s_wa1t[64*40];  // Wa1^T [u][e], B-frag layout
  __shared__ __align__(16) float s_l2[4*16*17];  // layer2 partials [w][q][e' pad17]
  __shared__ __align__(16) float s_o[16*132];    // output transpose [q][c pad132]
  __shared__ float s_pt[8][12];
  __shared__ float s_redA[16][4];  // mask partials per wave
  __shared__ float s_redB[16][4];  // logit max per wave
  __shared__ float s_redC[16][4];  // exp sums per wave
  __shared__ float s_rs[16];       // sigmoid(mask)/sum per q row
  // LDS ~37.3 KB -> 4 blocks/CU

  const int tid  = threadIdx.x;
  const int w    = tid >> 6;        // wave 0..3
  const int lane = tid & 63;
  const int quad = lane >> 4;
  const int l15  = lane & 15;
  const int b    = blockIdx.y;
  const int qt0  = blockIdx.x * QT_;
  const int q16  = tid >> 4, l16 = tid & 15;   // combine-phase mapping

  // ---- one-time staging ----
  float wcol[15];
  #pragma unroll
  for (int i=0;i<15;i++) wcol[i] = Wq1[i*256+tid];
  const float b1v  = bq1[tid];
  const float bq2a = bq2[l16], bq2b = bq2[l16+16];
  const float wa2v = Wa2[w*16 + l15];
  const float ba2v = ba2[0];
  {  // Wa1 [32e][64u] f32 -> s_wa1t [u][e] bf16
    int e = tid >> 3, u0 = (tid & 7) * 8;
    float4 wA = *(const float4*)&Wa1[e*64 + u0];
    float4 wB = *(const float4*)&Wa1[e*64 + u0 + 4];
    s_wa1t[(u0+0)*40+e]=__float2bfloat16(wA.x); s_wa1t[(u0+1)*40+e]=__float2bfloat16(wA.y);
    s_wa1t[(u0+2)*40+e]=__float2bfloat16(wA.z); s_wa1t[(u0+3)*40+e]=__float2bfloat16(wA.w);
    s_wa1t[(u0+4)*40+e]=__float2bfloat16(wB.x); s_wa1t[(u0+5)*40+e]=__float2bfloat16(wB.y);
    s_wa1t[(u0+6)*40+e]=__float2bfloat16(wB.z); s_wa1t[(u0+7)*40+e]=__float2bfloat16(wB.w);
  }
  if (tid < 8) {
    float mo[12], mq[12], pt[12];
    #pragma unroll
    for (int i=0;i<12;i++) mo[i] = pose_o[(b*8+tid)*12+i];
    #pragma unroll
    for (int i=0;i<12;i++) mq[i] = pose_q[b*12+i];
    relpose(mo, mq, pt);
    #pragma unroll
    for (int i=0;i<12;i++) s_pt[tid][i] = pt[i];
  }

  float acc[2][4];
  #pragma unroll
  for (int t2=0;t2<2;t2++)
    #pragma unroll
    for (int r=0;r<4;r++) acc[t2][r] = 0.f;

  __syncthreads();

  for (int n=0;n<8;n++) {
    const int bn = b*8+n;
    // ---- phase 1: layer-1 hidden (VALU), thread owns h=tid ----
    {
      float base = b1v;
      #pragma unroll
      for (int i=0;i<12;i++) base = fmaf(s_pt[n][i], wcol[i], base);
      #pragma unroll
      for (int q=0;q<16;q++) {
        int qg = qt0+q;
        float c0 = (float)(qg>>8) * 0.2f;
        float c1 = -1.f + (float)((qg>>4)&15)*(2.f/15.f);
        float c2 = -1.f + (float)(qg&15)*(2.f/15.f);
        float hv = fmaf(c2, wcol[14], fmaf(c1, wcol[13], fmaf(c0, wcol[12], base)));
        s_h[q*264 + tid] = __float2bfloat16(fmaxf(hv, 0.f));
      }
    }
    __syncthreads();                                     // B1
    // ---- phase 1b: layer-2 MFMA. wave w: e-tile (w&1), K-half (w>>1) ----
    {
      const int tw = w & 1, kh = w >> 1;
      ffrag C = {0.f,0.f,0.f,0.f};
      #pragma unroll
      for (int s=kh*4; s<kh*4+4; s++) {
        bfrag A = *(const bfrag*)&s_h[l15*264 + s*32 + quad*8];
        bfrag Bf = *(const bfrag*)&ws_w2t[(tw*16 + l15)*256 + s*32 + quad*8];
        C = __builtin_amdgcn_mfma_f32_16x16x32_bf16(A, Bf, C, 0, 0, 0);
      }
      #pragma unroll
      for (int r=0;r<4;r++)
        s_l2[w*272 + (quad*4+r)*17 + l15] = C[r];
    }
    __syncthreads();                                     // B2
    // ---- phase 2: combine partials -> emb_q bf16 A-frag ----
    {
      float v0 = s_l2[0*272 + q16*17 + l16] + s_l2[2*272 + q16*17 + l16] + bq2a;
      float v1 = s_l2[1*272 + q16*17 + l16] + s_l2[3*272 + q16*17 + l16] + bq2b;
      s_eqA[q16*40 + l16]      = __float2bfloat16(v0);
      s_eqA[q16*40 + l16 + 16] = __float2bfloat16(v1);
    }
    __syncthreads();                                     // B3
    // ---- phase 3: logits MFMA (4 key-tiles/wave) + mask MFMA (1 u-tile/wave) ----
    float S[4][4];
    {
      bfrag Aq = *(const bfrag*)&s_eqA[l15*40 + quad*8];
      #pragma unroll
      for (int t=0;t<4;t++) {
        int kt = w*4 + t;
        bfrag Bo = *(const bfrag*)&ws_eo[(kt*16 + l15)*32 + quad*8];
        ffrag C = {0.f,0.f,0.f,0.f};
        C = __builtin_amdgcn_mfma_f32_16x16x32_bf16(Aq, Bo, C, 0, 0, 0);
        #pragma unroll
        for (int r=0;r<4;r++) S[t][r] = C[r];
      }
      // mask: h2[q][u=w*16+l15]
      bfrag Bw = *(const bfrag*)&s_wa1t[(w*16 + l15)*40 + quad*8];
      ffrag Cm = {0.f,0.f,0.f,0.f};
      Cm = __builtin_amdgcn_mfma_f32_16x16x32_bf16(Aq, Bw, Cm, 0, 0, 0);
      #pragma unroll
      for (int r=0;r<4;r++) {
        float mp = fmaxf(Cm[r], 0.f) * wa2v;
        #pragma unroll
        for (int m=1; m<16; m<<=1) mp += __shfl_xor(mp, m);
        if (l15 == 0) s_redA[quad*4+r][w] = mp;
      }
      // per-q max over this wave's 64 keys
      #pragma unroll
      for (int r=0;r<4;r++) {
        float mx = fmaxf(fmaxf(S[0][r],S[1][r]), fmaxf(S[2][r],S[3][r]));
        #pragma unroll
        for (int m=1; m<16; m<<=1) mx = fmaxf(mx, __shfl_xor(mx, m));
        if (l15 == 0) s_redB[quad*4+r][w] = mx;
      }
    }
    __syncthreads();                                     // B4
    // ---- phase 3b: exp, sums, P bf16 ----
    {
      #pragma unroll
      for (int r=0;r<4;r++) {
        int q = quad*4+r;
        float rmax = fmaxf(fmaxf(s_redB[q][0],s_redB[q][1]),
                           fmaxf(s_redB[q][2],s_redB[q][3]));
        float sum = 0.f;
        #pragma unroll
        for (int t=0;t<4;t++) {
          float e = __expf(S[t][r] - rmax);
          S[t][r] = e;
          sum += e;
          s_p[q*264 + w*64 + t*16 + l15] = __float2bfloat16(e);
        }
        #pragma unroll
        for (int m=1; m<16; m<<=1) sum += __shfl_xor(sum, m);
        if (l15 == 0) s_redC[q][w] = sum;
      }
    }
    __syncthreads();                                     // B5
    if (tid < 16) {
      int q = tid;
      float msum = ba2v + s_redA[q][0] + s_redA[q][1] + s_redA[q][2] + s_redA[q][3];
      float ssum = s_redC[q][0] + s_redC[q][1] + s_redC[q][2] + s_redC[q][3];
      s_rs[q] = sigmoidf_(msum) / ssum;
    }
    __syncthreads();                                     // B6
    // ---- phase 4: vatt MFMA. wave w: c-tiles 2w, 2w+1; K=256 in 8 steps ----
    {
      ffrag C0 = {0.f,0.f,0.f,0.f}, C1 = {0.f,0.f,0.f,0.f};
      const int c0r = (2*w)*16 + l15, c1r = (2*w+1)*16 + l15;
      #pragma unroll
      for (int s=0;s<8;s++) {
        bfrag Ap = *(const bfrag*)&s_p[l15*264 + s*32 + quad*8];
        bfrag B0, B1;
        if (PRE) {
          B0 = *(const bfrag*)&vbf[((size_t)bn*128 + c0r)*256 + s*32 + quad*8];
          B1 = *(const bfrag*)&vbf[((size_t)bn*128 + c1r)*256 + s*32 + quad*8];
        } else {
          const float* p0 = &vc[((size_t)bn*128 + c0r)*256 + s*32 + quad*8];
          const float* p1 = &vc[((size_t)bn*128 + c1r)*256 + s*32 + quad*8];
          float4 a0 = *(const float4*)p0, a1 = *(const float4*)(p0+4);
          float4 b0 = *(const float4*)p1, b1 = *(const float4*)(p1+4);
          B0[0]=(__bf16)a0.x; B0[1]=(__bf16)a0.y; B0[2]=(__bf16)a0.z; B0[3]=(__bf16)a0.w;
          B0[4]=(__bf16)a1.x; B0[5]=(__bf16)a1.y; B0[6]=(__bf16)a1.z; B0[7]=(__bf16)a1.w;
          B1[0]=(__bf16)b0.x; B1[1]=(__bf16)b0.y; B1[2]=(__bf16)b0.z; B1[3]=(__bf16)b0.w;
          B1[4]=(__bf16)b1.x; B1[5]=(__bf16)b1.y; B1[6]=(__bf16)b1.z; B1[7]=(__bf16)b1.w;
        }
        C0 = __builtin_amdgcn_mfma_f32_16x16x32_bf16(Ap, B0, C0, 0, 0, 0);
        C1 = __builtin_amdgcn_mfma_f32_16x16x32_bf16(Ap, B1, C1, 0, 0, 0);
      }
      #pragma unroll
      for (int r=0;r<4;r++) {
        float rsv = s_rs[quad*4+r];
        acc[0][r] = fmaf(rsv, C0[r], acc[0][r]);
        acc[1][r] = fmaf(rsv, C1[r], acc[1][r]);
      }
    }
    // next-n phase1 writes s_h (last read before B2); B1 of next iter orders everything
  }
  // ---- epilogue: sigmoid -> LDS transpose -> coalesced f32 stores ----
  #pragma unroll
  for (int t2=0;t2<2;t2++)
    #pragma unroll
    for (int r=0;r<4;r++)
      s_o[(quad*4+r)*132 + (2*w+t2)*16 + l15] = sigmoidf_(acc[t2][r]);
  __syncthreads();
  {
    int c = tid >> 1, qh = (tid & 1) * 8;
    float o[8];
    #pragma unroll
    for (int j=0;j<8;j++) o[j] = s_o[(qh+j)*132 + c];
    float* dst = &out[(size_t)b*196608 + (size_t)c*1536 + qt0 + qh];
    *(float4*)dst     = make_float4(o[0],o[1],o[2],o[3]);
    *(float4*)(dst+4) = make_float4(o[4],o[5],o[6],o[7]);
  }
}

extern "C" void kernel_launch(void* const* d_in, const int* in_sizes, int n_in,
                              void* d_out, int out_size, void* d_ws, size_t ws_size,
                              hipStream_t stream) {
  const float* view_cell = (const float*)d_in[0];
  const float* pose_o = (const float*)d_in[1];
  const float* pose_q = (const float*)d_in[2];
  const float* Wk1 = (const float*)d_in[3];
  const float* bk1 = (const float*)d_in[4];
  const float* Wk2 = (const float*)d_in[5];
  const float* bk2 = (const float*)d_in[6];
  const float* Wq1 = (const float*)d_in[7];
  const float* bq1 = (const float*)d_in[8];
  const float* Wq2 = (const float*)d_in[9];
  const float* bq2 = (const float*)d_in[10];
  const float* Wa1 = (const float*)d_in[11];
  const float* ba1 = (const float*)d_in[12];
  const float* Wa2 = (const float*)d_in[13];
  const float* ba2 = (const float*)d_in[14];

  float* out = (float*)d_out;
  float* out_qo = out + 6291456;          // 32*128*1536
  float* out_qq = out + 6291456 + 1792;   // + 32*8*7

  bf16* ws_eo  = (bf16*)((char*)d_ws + WS_EO);
  bf16* ws_w2t = (bf16*)((char*)d_ws + WS_W2T);
  bf16* ws_vbf = (bf16*)((char*)d_ws + WS_VBF);

  const bool pre = ws_size >= (size_t)(WS_VBF + 256u*128u*256u*2u);

  hipLaunchKernelGGL(k_pose, dim3(1), dim3(256), 0, stream,
                     pose_o, pose_q, out_qo, out_qq);
  hipLaunchKernelGGL(k_embo, dim3(1), dim3(256), 0, stream,
                     Wk1, bk1, Wk2, bk2, ws_eo);
  hipLaunchKernelGGL(k_w2t, dim3(1), dim3(256), 0, stream, Wq2, ws_w2t);

  if (pre) {
    hipLaunchKernelGGL(k_vconv, dim3(4096), dim3(256), 0, stream, view_cell, ws_vbf);
    hipLaunchKernelGGL((k_main<true>), dim3(96, 32), dim3(256), 0, stream,
                       view_cell, ws_vbf, pose_o, pose_q, ws_eo, ws_w2t,
                       Wq1, bq1, bq2, Wa1, ba1, Wa2, ba2, out);
  } else {
    hipLaunchKernelGGL((k_main<false>), dim3(96, 32), dim3(256), 0, stream,
                       view_cell, ws_vbf, pose_o, pose_q, ws_eo, ws_w2t,
                       Wq1, bq1, bq2, Wa1, ba1, Wa2, ba2, out);
  }
}